// Round 7
// baseline (1404.118 us; speedup 1.0000x reference)
//
#include <hip/hip_runtime.h>
#include <hip/hip_bf16.h>
#include <math.h>
#include <stdint.h>

// Problem constants
constexpr int N_ROWS = 32768;
constexpr int K_DIM  = 4096;
constexpr int R_DIM  = 256;
constexpr int KP     = 3 * R_DIM;   // 768: split-K' [hi|hi|lo] x [hi|lo|hi]

typedef __bf16 bf16x8 __attribute__((ext_vector_type(8)));
typedef float  f32x4  __attribute__((ext_vector_type(4)));
typedef unsigned short u16x8 __attribute__((ext_vector_type(8)));
typedef unsigned short u16x4 __attribute__((ext_vector_type(4)));

// ---- bf16 helpers (round-to-nearest-even) ----
__device__ __forceinline__ unsigned short f2bf(float x) {
    unsigned u = __float_as_uint(x);
    u += 0x7fffu + ((u >> 16) & 1u);
    return (unsigned short)(u >> 16);
}
__device__ __forceinline__ float bf2f(unsigned short h) {
    return __uint_as_float((unsigned)h << 16);
}

// ---- async global->LDS, 16B/lane, LDS dest = wave-uniform base + lane*16
__device__ __forceinline__ void gl2lds16(const void* gptr, void* lptr) {
    __builtin_amdgcn_global_load_lds(
        (const __attribute__((address_space(1))) unsigned int*)gptr,
        (__attribute__((address_space(3))) unsigned int*)lptr,
        16, 0, 0);
}

// ===========================================================================
// K2: MFMA NT GEMM: C[m,n] = sum_k A[m,k]*B[n,k], bf16 in, fp32 out.
// 128x128 tile, BK=32, 4 waves (2x2 of 64x64), 16x16x32 MFMA.
// Grid: x = N-tile (fast-varying -> A-strip L2 reuse), y = M-tile.
// ===========================================================================
__global__ __launch_bounds__(256)
void gemm_mfma_nt(const unsigned short* __restrict__ A,
                  const unsigned short* __restrict__ B,
                  float* __restrict__ C, int M, int N, int Kc)
{
    __shared__ __align__(16) unsigned short As[128 * 32];
    __shared__ __align__(16) unsigned short Bs[128 * 32];

    const int tid  = threadIdx.x;
    const int wave = tid >> 6, lane = tid & 63;
    const int wm = wave >> 1, wn = wave & 1;
    const long m0 = (long)blockIdx.y * 128;
    const long n0 = (long)blockIdx.x * 128;

    f32x4 acc[4][4] = {};

    const int srow  = lane >> 2;
    const int skoff = (lane & 3) * 8;
    const int c0 = wave, c1 = wave + 4;
    const int kq = (lane >> 4) * 8;
    const int mr = lane & 15;

    for (int k0 = 0; k0 < Kc; k0 += 32) {
        gl2lds16(A + (m0 + c0 * 16 + srow) * (long)Kc + k0 + skoff, &As[c0 * 512]);
        gl2lds16(A + (m0 + c1 * 16 + srow) * (long)Kc + k0 + skoff, &As[c1 * 512]);
        gl2lds16(B + (n0 + c0 * 16 + srow) * (long)Kc + k0 + skoff, &Bs[c0 * 512]);
        gl2lds16(B + (n0 + c1 * 16 + srow) * (long)Kc + k0 + skoff, &Bs[c1 * 512]);
        __syncthreads();

        bf16x8 af[4], bfr[4];
#pragma unroll
        for (int t = 0; t < 4; ++t) {
            af[t]  = *(const bf16x8*)&As[(wm * 64 + t * 16 + mr) * 32 + kq];
            bfr[t] = *(const bf16x8*)&Bs[(wn * 64 + t * 16 + mr) * 32 + kq];
        }
#pragma unroll
        for (int i = 0; i < 4; ++i)
#pragma unroll
            for (int j = 0; j < 4; ++j)
                acc[i][j] = __builtin_amdgcn_mfma_f32_16x16x32_bf16(
                    af[i], bfr[j], acc[i][j], 0, 0, 0);
        __syncthreads();
    }

    const int col = lane & 15, rquad = (lane >> 4) * 4;
#pragma unroll
    for (int i = 0; i < 4; ++i) {
        const long mrow = m0 + wm * 64 + i * 16 + rquad;
#pragma unroll
        for (int j = 0; j < 4; ++j) {
            float* p = C + mrow * (long)N + n0 + wn * 64 + j * 16 + col;
#pragma unroll
            for (int r = 0; r < 4; ++r) p[(long)r * N] = acc[i][j][r];
        }
    }
}

// ===========================================================================
// Tail fused v3: per 32-row strip (1024 blocks, 4/CU) —
//  stats: two-pass chain-free (max, then sum-exp with known max).
//  PV: single-barrier double-buffered loop. A prefetched from global into
//  registers one iter ahead; exp/writeback/pack AFTER the MFMAs (latency
//  hides under compute). LT double-buffered via global_load_lds.
// ===========================================================================
__global__ __launch_bounds__(256)
void fused_saw3(float* __restrict__ Mio, const unsigned short* __restrict__ LT,
                float* __restrict__ C)
{
    __shared__ __align__(16) unsigned short As[2][32 * 32];
    __shared__ __align__(16) unsigned short Bs[2][256 * 32];
    __shared__ float sm[32][8], ss[32][8], rowm[32], rowiv[32];

    const int tid = threadIdx.x, wave = tid >> 6, lane = tid & 63;
    const long m0 = (long)blockIdx.x * 32;
    const int arow = tid >> 3, alane = tid & 7;
    float* Ar = Mio + (m0 + arow) * (long)K_DIM + alane * 4;

    // ---- stats pass 1: max (4 independent accumulators, no chain)
    float4 mx = make_float4(-3.4e38f, -3.4e38f, -3.4e38f, -3.4e38f);
#pragma unroll 8
    for (int q = 0; q < 128; ++q) {
        float4 v = *(const float4*)(Ar + 32 * q);
        mx.x = fmaxf(mx.x, v.x); mx.y = fmaxf(mx.y, v.y);
        mx.z = fmaxf(mx.z, v.z); mx.w = fmaxf(mx.w, v.w);
    }
    sm[arow][alane] = fmaxf(fmaxf(mx.x, mx.y), fmaxf(mx.z, mx.w));
    __syncthreads();
    float m = sm[arow][0];
#pragma unroll
    for (int t = 1; t < 8; ++t) m = fmaxf(m, sm[arow][t]);

    // ---- stats pass 2: sum-exp (known max; exps independent; L2-warm)
    float4 sx = make_float4(0.f, 0.f, 0.f, 0.f);
#pragma unroll 8
    for (int q = 0; q < 128; ++q) {
        float4 v = *(const float4*)(Ar + 32 * q);
        sx.x += __expf(v.x - m); sx.y += __expf(v.y - m);
        sx.z += __expf(v.z - m); sx.w += __expf(v.w - m);
    }
    ss[arow][alane] = (sx.x + sx.y) + (sx.z + sx.w);
    __syncthreads();
    if (alane == 0) {
        float S = 0.f;
#pragma unroll
        for (int t = 0; t < 8; ++t) S += ss[arow][t];
        rowm[arow] = m;
        rowiv[arow] = 1.f / S;
    }
    __syncthreads();
    const float rm = rowm[arow], ri = rowiv[arow];

    // ---- PV loop
    const int srow = lane >> 2, skoff = (lane & 3) * 8;
    const int fr = lane & 15, kq = (lane >> 4) * 8;

    f32x4 acc[2][4] = {};

    auto stageB = [&](int buf, int k0) {
#pragma unroll
        for (int c4 = 0; c4 < 4; ++c4) {
            const int c = wave * 4 + c4;
            gl2lds16(LT + (c * 16 + srow) * (long)K_DIM + k0 + skoff,
                     &Bs[buf][c * 512]);
        }
    };
    auto stageA = [&](int buf, int k0, float4 v) {
        float4 a;
        a.x = __expf(v.x - rm) * ri; a.y = __expf(v.y - rm) * ri;
        a.z = __expf(v.z - rm) * ri; a.w = __expf(v.w - rm) * ri;
        *(float4*)(Ar + k0) = a;                 // fp32 A_I write-back
        u16x4 u;
        u[0] = f2bf(a.x); u[1] = f2bf(a.y); u[2] = f2bf(a.z); u[3] = f2bf(a.w);
        *(u16x4*)&As[buf][arow * 32 + alane * 4] = u;
    };

    // prologue: buffer 0
    stageB(0, 0);
    stageA(0, 0, *(const float4*)(Ar));
    __syncthreads();

    int cb = 0;
#pragma unroll 1
    for (int it = 0; it < 128; ++it) {
        const int k0 = it * 32;
        const bool more = (it + 1 < 128);
        float4 vn;
        if (more) {
            vn = *(const float4*)(Ar + k0 + 32);   // A prefetch (registers)
            stageB(cb ^ 1, k0 + 32);               // LT prefetch (DMA)
        }

        bf16x8 af0 = *(const bf16x8*)&As[cb][fr * 32 + kq];
        bf16x8 af1 = *(const bf16x8*)&As[cb][(16 + fr) * 32 + kq];
        bf16x8 bfr[4];
#pragma unroll
        for (int j = 0; j < 4; ++j)
            bfr[j] = *(const bf16x8*)&Bs[cb][(wave * 64 + j * 16 + fr) * 32 + kq];
#pragma unroll
        for (int j = 0; j < 4; ++j) {
            acc[0][j] = __builtin_amdgcn_mfma_f32_16x16x32_bf16(
                af0, bfr[j], acc[0][j], 0, 0, 0);
            acc[1][j] = __builtin_amdgcn_mfma_f32_16x16x32_bf16(
                af1, bfr[j], acc[1][j], 0, 0, 0);
        }

        if (more) stageA(cb ^ 1, k0 + 32, vn);     // exp+pack after MFMAs
        __syncthreads();
        cb ^= 1;
    }

    const int col = lane & 15, rq = (lane >> 4) * 4;
#pragma unroll
    for (int i = 0; i < 2; ++i)
#pragma unroll
        for (int j = 0; j < 4; ++j)
#pragma unroll
            for (int r = 0; r < 4; ++r)
                C[(m0 + i * 16 + rq + r) * (long)R_DIM + wave * 64 + j * 16 + col]
                    = acc[i][j][r];
}

// ===========================================================================
// Prep kernels
// ===========================================================================
// Hs = [H_hi | H_hi | H_lo]  (N_ROWS x 768) — from the exact input H
__global__ __launch_bounds__(256)
void prep_hs(const float* __restrict__ H, unsigned short* __restrict__ Hs)
{
    const long i = (long)blockIdx.x * 256 + threadIdx.x;
    const long n = i >> 8; const int r = (int)(i & 255);
    const float x = H[i];
    const unsigned short hi = f2bf(x);
    const unsigned short lo = f2bf(x - bf2f(hi));
    unsigned short* row = Hs + n * KP;
    row[r] = hi; row[R_DIM + r] = hi; row[2 * R_DIM + r] = lo;
}

// Qs = [Q_hi | Q_lo | Q_hi]  (K_DIM x 768) — from Qt (K_DIM x R_DIM fp32)
__global__ __launch_bounds__(256)
void prep_qs(const float* __restrict__ Qt, unsigned short* __restrict__ Qs)
{
    const long i = (long)blockIdx.x * 256 + threadIdx.x;
    const long k = i >> 8; const int r = (int)(i & 255);
    const float x = Qt[i];
    const unsigned short hi = f2bf(x);
    const unsigned short lo = f2bf(x - bf2f(hi));
    unsigned short* row = Qs + k * KP;
    row[r] = hi; row[R_DIM + r] = lo; row[2 * R_DIM + r] = hi;
}

// LDS-tile transpose: LT[r][k] = bf16(L[k][r]); coalesced both sides.
__global__ __launch_bounds__(256)
void prep_LT(const float* __restrict__ L, unsigned short* __restrict__ LT)
{
    __shared__ unsigned short t[64][66];
    const int k0 = blockIdx.x * 64;
    const int r0 = blockIdx.y * 64;
    const int tid = threadIdx.x;
#pragma unroll
    for (int q = 0; q < 16; ++q) {
        const int e = q * 256 + tid;
        const int kk = e >> 6, rr = e & 63;
        t[rr][kk] = f2bf(L[(long)(k0 + kk) * R_DIM + r0 + rr]);
    }
    __syncthreads();
#pragma unroll
    for (int q = 0; q < 16; ++q) {
        const int e = q * 256 + tid;
        const int rr = e >> 6, kk = e & 63;
        LT[(long)(r0 + rr) * K_DIM + k0 + kk] = t[rr][kk];
    }
}

// ===========================================================================
// fp32 VALU GEMM — used for Qt = L @ W_I^T (tiny) and the no-ws fallback.
// ===========================================================================
template<bool BT>
__global__ __launch_bounds__(256)
void gemm128(const float* __restrict__ A, const float* __restrict__ B,
             float* __restrict__ C, int M, int N, int Kc)
{
    __shared__ __align__(16) float Asl[16][132];
    __shared__ __align__(16) float Bsl[16][132];
    const int tid = threadIdx.x;
    const int tx = tid & 15, ty = tid >> 4;
    const long m0 = (long)blockIdx.x * 128;
    const long n0 = (long)blockIdx.y * 128;
    float acc[8][8];
#pragma unroll
    for (int i = 0; i < 8; ++i)
#pragma unroll
        for (int j = 0; j < 8; ++j) acc[i][j] = 0.f;
    for (int k0 = 0; k0 < Kc; k0 += 16) {
#pragma unroll
        for (int q = 0; q < 2; ++q) {
            int fi = tid + 256 * q, row = fi >> 2, col = (fi & 3) * 4;
            float4 v = *(const float4*)(A + (m0 + row) * (long)Kc + k0 + col);
            Asl[col + 0][row] = v.x; Asl[col + 1][row] = v.y;
            Asl[col + 2][row] = v.z; Asl[col + 3][row] = v.w;
        }
        if (BT) {
#pragma unroll
            for (int q = 0; q < 2; ++q) {
                int fi = tid + 256 * q, row = fi >> 2, col = (fi & 3) * 4;
                float4 v = *(const float4*)(B + (n0 + row) * (long)Kc + k0 + col);
                Bsl[col + 0][row] = v.x; Bsl[col + 1][row] = v.y;
                Bsl[col + 2][row] = v.z; Bsl[col + 3][row] = v.w;
            }
        } else {
#pragma unroll
            for (int q = 0; q < 2; ++q) {
                int fi = tid + 256 * q, row = fi >> 5, col = (fi & 31) * 4;
                float4 v = *(const float4*)(B + (k0 + row) * (long)N + n0 + col);
                *(float4*)&Bsl[row][col] = v;
            }
        }
        __syncthreads();
#pragma unroll
        for (int kk = 0; kk < 16; ++kk) {
            float a[8], b[8];
            *(float4*)&a[0] = *(const float4*)&Asl[kk][ty * 8];
            *(float4*)&a[4] = *(const float4*)&Asl[kk][ty * 8 + 4];
            *(float4*)&b[0] = *(const float4*)&Bsl[kk][tx * 8];
            *(float4*)&b[4] = *(const float4*)&Bsl[kk][tx * 8 + 4];
#pragma unroll
            for (int i = 0; i < 8; ++i)
#pragma unroll
                for (int j = 0; j < 8; ++j)
                    acc[i][j] = fmaf(a[i], b[j], acc[i][j]);
        }
        __syncthreads();
    }
#pragma unroll
    for (int i = 0; i < 8; ++i) {
        float* p = C + (m0 + ty * 8 + i) * (long)N + n0 + tx * 8;
        *(float4*)p       = make_float4(acc[i][0], acc[i][1], acc[i][2], acc[i][3]);
        *(float4*)(p + 4) = make_float4(acc[i][4], acc[i][5], acc[i][6], acc[i][7]);
    }
}

__global__ __launch_bounds__(256)
void softmax_rows(float* __restrict__ Mio)
{
    const long n  = blockIdx.x;
    float* row    = Mio + n * (long)K_DIM;
    const int tid = threadIdx.x;
    float4 v[4];
    float lmax = -3.4e38f;
#pragma unroll
    for (int q = 0; q < 4; ++q) {
        v[q] = ((const float4*)row)[tid + 256 * q];
        lmax = fmaxf(lmax, fmaxf(fmaxf(v[q].x, v[q].y), fmaxf(v[q].z, v[q].w)));
    }
    __shared__ float redmax[4], redsum[4];
#pragma unroll
    for (int off = 32; off > 0; off >>= 1)
        lmax = fmaxf(lmax, __shfl_xor(lmax, off));
    if ((tid & 63) == 0) redmax[tid >> 6] = lmax;
    __syncthreads();
    const float gmax = fmaxf(fmaxf(redmax[0], redmax[1]), fmaxf(redmax[2], redmax[3]));
    float lsum = 0.f;
#pragma unroll
    for (int q = 0; q < 4; ++q) {
        v[q].x = __expf(v[q].x - gmax); v[q].y = __expf(v[q].y - gmax);
        v[q].z = __expf(v[q].z - gmax); v[q].w = __expf(v[q].w - gmax);
        lsum += v[q].x + v[q].y + v[q].z + v[q].w;
    }
#pragma unroll
    for (int off = 32; off > 0; off >>= 1)
        lsum += __shfl_xor(lsum, off);
    if ((tid & 63) == 0) redsum[tid >> 6] = lsum;
    __syncthreads();
    const float inv = 1.f / (redsum[0] + redsum[1] + redsum[2] + redsum[3]);
#pragma unroll
    for (int q = 0; q < 4; ++q) {
        v[q].x *= inv; v[q].y *= inv; v[q].z *= inv; v[q].w *= inv;
        ((float4*)row)[tid + 256 * q] = v[q];
    }
}

// ===========================================================================
extern "C" void kernel_launch(void* const* d_in, const int* in_sizes, int n_in,
                              void* d_out, int out_size, void* d_ws, size_t ws_size,
                              hipStream_t stream)
{
    const float* H  = (const float*)d_in[0];
    const float* L  = (const float*)d_in[1];
    const float* Wi = (const float*)d_in[2];

    float* Cout = (float*)d_out;                           // N x R
    float* Aout = (float*)d_out + (size_t)N_ROWS * R_DIM;  // N x K

    const size_t szHs = (size_t)N_ROWS * KP * 2;     // 48 MiB
    const size_t szQs = (size_t)K_DIM * KP * 2;      //  6 MiB
    const size_t szLT = (size_t)R_DIM * K_DIM * 2;   //  2 MiB

    if (ws_size >= szHs + szQs + szLT) {
        unsigned short* Hs = (unsigned short*)d_ws;
        unsigned short* Qs = (unsigned short*)((char*)d_ws + szHs);
        unsigned short* LT = (unsigned short*)((char*)d_ws + szHs + szQs);
        float* Qt = Cout;   // K_DIM x R_DIM fp32 scratch in the C slot (4 MiB)

        // Qt = L @ W_I^T (0.5 GF, tiny)
        gemm128<true><<<dim3(K_DIM / 128, R_DIM / 128), 256, 0, stream>>>(
            L, Wi, Qt, K_DIM, R_DIM, R_DIM);
        // Split operands
        prep_hs<<<dim3((N_ROWS * R_DIM) / 256), 256, 0, stream>>>(H, Hs);
        prep_qs<<<dim3((K_DIM * R_DIM) / 256), 256, 0, stream>>>(Qt, Qs);
        prep_LT<<<dim3(K_DIM / 64, R_DIM / 64), 256, 0, stream>>>(L, LT);
        // K2: logits M = Hs . Qs^T  (3-term split bf16 MFMA, K'=768)
        gemm_mfma_nt<<<dim3(K_DIM / 128, N_ROWS / 128), 256, 0, stream>>>(
            Hs, Qs, Aout, N_ROWS, K_DIM, KP);
        // Tail: stats + softmax-in-place + C = A@L (overwrites Qt)
        fused_saw3<<<dim3(N_ROWS / 32), 256, 0, stream>>>(Aout, LT, Cout);
    } else {
        // Fallback: round-1 fp32 path
        gemm128<false><<<dim3(N_ROWS / 128, R_DIM / 128), 256, 0, stream>>>(
            H, Wi, Cout, N_ROWS, R_DIM, R_DIM);
        gemm128<true><<<dim3(N_ROWS / 128, K_DIM / 128), 256, 0, stream>>>(
            Cout, L, Aout, N_ROWS, K_DIM, R_DIM);
        softmax_rows<<<dim3(N_ROWS), 256, 0, stream>>>(Aout);
        gemm128<false><<<dim3(N_ROWS / 128, R_DIM / 128), 256, 0, stream>>>(
            Aout, L, Cout, N_ROWS, R_DIM, K_DIM);
    }
}